// Round 1
// baseline (1555.417 us; speedup 1.0000x reference)
//
#include <hip/hip_runtime.h>

// ConvLSTM cell on MI355X (gfx950) — round 4.
// Implicit GEMM M=256 (4 gates x 64 oc), K=864 (96ch x 9 taps), N=131072.
// bf16 MFMA 32x32x16. Wave tile M=64 (4 gates x 16 oc -> lane-local LSTM
// epilogue) x N=64, acc = 64 AGPRs.
// Round-4 change: 16-wave blocks (4 og x 4 nh, 4 output rows), grid 512 =
// exactly 2 blocks/CU resident (32 waves/CU, no churn/tail). Per-tap 48 KB
// A-slab stage now amortized over 384 MFMAs (2x), and the co-resident block
// hides each stage/barrier phase.
// A: per-tap 48KB LDS slab via global_load_lds; frags via ds_read_b128.
// B: direct global dwordx4 from P'[b][yy][pc12][xx66][8ch] (coalesced, L1/L2).

#define B_   32
#define CIN  32
#define HC_  64
#define HH   64
#define WW   64

#define A_ELEMS (9 * 8 * 6 * 64 * 8)     // 221184 bf16 = 256 x 864 packed A
#define P_ROW   (12 * 66 * 8)            // shorts per P' row = 6336
#define SLAB    24576                    // shorts per tap slab (48 KB)

typedef __attribute__((ext_vector_type(8)))  short  short8;
typedef __attribute__((ext_vector_type(16))) float  floatx16;

struct PackArgs {
    const float* wx[4]; const float* wh[4];
    const float* bx[4]; const float* bh[4];
};

__device__ __forceinline__ short f2bf(float f) {
    unsigned u = __float_as_uint(f);
    u += 0x7FFFu + ((u >> 16) & 1u);     // round-to-nearest-even
    return (short)(u >> 16);
}

__device__ __forceinline__ void gl_lds16(const short* g, short* l) {
    __builtin_amdgcn_global_load_lds(
        (const __attribute__((address_space(1))) unsigned int*)g,
        (__attribute__((address_space(3))) unsigned int*)l, 16, 0, 0);
}

// ---- pack A: [tap 9][s 8][kk 6][lane 64][j 8] ------------------------------
// s = og*2+fi ; m32 = lane&31 ; gate = 2*fi + (m32>>4) ; oc = og*16 + (m32&15)
// c = kk*16 + (lane>>5)*8 + j  (A-operand: m = lane&31, k = (lane>>5)*8+j)
__global__ __launch_bounds__(256) void pack_weights(PackArgs pa, short* a_pk, float* bias) {
    int idx = blockIdx.x * 256 + threadIdx.x;
    if (idx < A_ELEMS) {
        int j    = idx & 7;
        int lane = (idx >> 3) & 63;
        int rest = idx >> 9;             // (tap*8+s)*6 + kk
        int kk   = rest % 6;
        int rest2 = rest / 6;
        int s    = rest2 % 8;
        int tap  = rest2 / 8;
        int og = s >> 1, fi = s & 1;
        int m32 = lane & 31;
        int gate = 2 * fi + (m32 >> 4);
        int oc   = og * 16 + (m32 & 15);
        int c    = kk * 16 + (lane >> 5) * 8 + j;
        int ky = tap / 3, kx = tap - 3 * ky;
        float v = (c < CIN)
            ? pa.wx[gate][((oc * CIN + c) * 3 + ky) * 3 + kx]
            : pa.wh[gate][((oc * HC_ + (c - CIN)) * 3 + ky) * 3 + kx];
        a_pk[idx] = f2bf(v);
    }
    if (idx < 256) {
        int gate = idx >> 6, oc = idx & 63;
        bias[idx] = pa.bx[gate][oc] + pa.bh[gate][oc];
    }
}

// ---- pack x||h -> P'[b][yy][pc 12][xx 66][8ch] bf16, zero borders ----------
__global__ __launch_bounds__(256) void pack_input(const float* __restrict__ x,
                                                  const float* __restrict__ h,
                                                  short* __restrict__ P) {
    const int yy = blockIdx.x, b = blockIdx.y;
    int4* prow4 = (int4*)(P + ((size_t)b * 66 + yy) * P_ROW);  // 792 chunks

    if (yy == 0 || yy == 65) {
        int4 z = {0, 0, 0, 0};
        for (int g = threadIdx.x; g < 792; g += 256) prow4[g] = z;
        return;
    }

    __shared__ short t[64 * 98];                     // [x][c], pad 96->98
    const int y = yy - 1;
    const int col = threadIdx.x & 63, cg = threadIdx.x >> 6;
    for (int c = cg; c < 96; c += 4) {
        float v = (c < CIN) ? x[((b * CIN + c) * HH + y) * WW + col]
                            : h[((b * HC_ + (c - CIN)) * HH + y) * WW + col];
        t[col * 98 + c] = f2bf(v);
    }
    __syncthreads();

    for (int g = threadIdx.x; g < 792; g += 256) {   // pc = g/66, xx = g%66
        int pc = g / 66, xx = g - 66 * pc;
        int4 val = {0, 0, 0, 0};
        if (xx >= 1 && xx <= 64) {
            const short* sp = &t[(xx - 1) * 98 + pc * 8];
            val.x = *(const int*)(sp + 0); val.y = *(const int*)(sp + 2);
            val.z = *(const int*)(sp + 4); val.w = *(const int*)(sp + 6);
        }
        prow4[g] = val;
    }
}

// ---- main: grid 512 = (b 32)x(rowgroup 16 of 4 rows), 1024 thr = 16 waves --
// wave = og(0..3) x nh(0..3): M-tile = 4 gates x 16 oc (og), N = row y0+nh,
// 64 cols. acc[fi][ns] (fi = gate-pair, ns = col-half), 64 AGPR total.
// 2 blocks/CU resident (LDS 2x48KB, regs 128/wave) -> stage/barrier phases of
// one block hide under the other block's MFMA stream.
__global__ __launch_bounds__(1024, 8) void convlstm_main(
    const short* __restrict__ P, const short* __restrict__ a_pk,
    const float* __restrict__ bias, const float* __restrict__ cell,
    float* __restrict__ out)
{
    __shared__ __align__(16) short As[SLAB];         // 48 KB -> 2 blocks/CU

    const int tid = threadIdx.x;
    const int b  = blockIdx.x >> 4;
    const int y0 = (blockIdx.x & 15) * 4;

    const int wv = tid >> 6, lane = tid & 63;
    const int ln31 = lane & 31, hg = lane >> 5;
    const int og = wv & 3, nh = wv >> 2;
    const int y = y0 + nh;

    floatx16 acc[2][2];
    #pragma unroll
    for (int fi = 0; fi < 2; ++fi)
        #pragma unroll
        for (int ns = 0; ns < 2; ++ns)
            #pragma unroll
            for (int q = 0; q < 16; ++q) acc[fi][ns][q] = 0.f;

    // wave-constant pieces
    const int a_base = og * 12 * 64 * 8 + lane * 8;          // + (fi*6+kk)*512
    const int lnoff  = (hg * 66 + ln31) * 8;                 // B per-lane offset

    for (int ky = 0; ky < 3; ++ky)
    for (int kx = 0; kx < 3; ++kx) {
        const int tap = ky * 3 + kx;
        // ---- stage A slab for this tap (3072 chunks / 1024 thr = 3 each)
        {
            const short* slab = a_pk + tap * SLAB;
            #pragma unroll
            for (int i = 0; i < 3; ++i) {
                int id = i * 1024 + tid;
                gl_lds16(slab + id * 8, As + (i * 1024 + wv * 64) * 8);
            }
        }
        __syncthreads();

        const short* Brow = P + ((size_t)(b * 66) + y + ky) * P_ROW + kx * 8 + lnoff;

        #pragma unroll
        for (int kk = 0; kk < 6; ++kk) {
            short8 a0 = *(const short8*)&As[a_base + (0 * 6 + kk) * 512];
            short8 a1 = *(const short8*)&As[a_base + (1 * 6 + kk) * 512];
            short8 b0 = *(const short8*)&Brow[(2 * kk * 66 + 0 ) * 8];
            short8 b1 = *(const short8*)&Brow[(2 * kk * 66 + 32) * 8];
            acc[0][0] = __builtin_amdgcn_mfma_f32_32x32x16_bf16(a0, b0, acc[0][0], 0, 0, 0);
            acc[0][1] = __builtin_amdgcn_mfma_f32_32x32x16_bf16(a0, b1, acc[0][1], 0, 0, 0);
            acc[1][0] = __builtin_amdgcn_mfma_f32_32x32x16_bf16(a1, b0, acc[1][0], 0, 0, 0);
            acc[1][1] = __builtin_amdgcn_mfma_f32_32x32x16_bf16(a1, b1, acc[1][1], 0, 0, 0);
        }
        __syncthreads();
    }

    // ---- lane-local LSTM epilogue --------------------------------------
    // C/D 32x32 map: col = ln31, row r32 = (r&3) + 4*hg + 8*(r>>2).
    // acc[fi][.] rows: r32<16 -> gate 2fi, oc16=r32 ; r32>=16 -> gate 2fi+1.
    const size_t plane = (size_t)B_ * HC_ * HH * WW;
    #pragma unroll
    for (int q = 0; q < 4; ++q)
    #pragma unroll
    for (int b8 = 0; b8 < 2; ++b8) {
        const int oc16 = q + 4 * hg + 8 * b8;
        const int oc = og * 16 + oc16;
        const float Bi = bias[oc],       Bf = bias[64 + oc];
        const float Bo = bias[128 + oc], Bg = bias[192 + oc];
        const int r_lo = q + 4 * b8, r_hi = q + 4 * (2 + b8);
        #pragma unroll
        for (int ns = 0; ns < 2; ++ns) {
            float zi = acc[0][ns][r_lo] + Bi;
            float zf = acc[0][ns][r_hi] + Bf;
            float zo = acc[1][ns][r_lo] + Bo;
            float zg = acc[1][ns][r_hi] + Bg;
            float ig = 1.f / (1.f + __expf(-zi));
            float fg = 1.f / (1.f + __expf(-zf));
            float sg = 1.f / (1.f + __expf(-zo));
            float e2 = __expf(2.f * zg);
            float gg = 1.f - 2.f / (e2 + 1.f);               // tanh(zg)
            const int x = ns * 32 + ln31;
            size_t off = ((size_t)(b * HC_ + oc) * HH + y) * WW + x;
            float cn = fg * cell[off] + ig * gg;
            float ec = __expf(2.f * cn);
            out[off] = sg * (1.f - 2.f / (ec + 1.f));        // h_new
            out[plane + off] = cn;                           // c_new
        }
    }
}

extern "C" void kernel_launch(void* const* d_in, const int* in_sizes, int n_in,
                              void* d_out, int out_size, void* d_ws, size_t ws_size,
                              hipStream_t stream) {
    PackArgs pa;
    pa.wx[0] = (const float*)d_in[3];  pa.bx[0] = (const float*)d_in[4];
    pa.wx[1] = (const float*)d_in[5];  pa.bx[1] = (const float*)d_in[6];
    pa.wx[2] = (const float*)d_in[7];  pa.bx[2] = (const float*)d_in[8];
    pa.wx[3] = (const float*)d_in[9];  pa.bx[3] = (const float*)d_in[10];
    pa.wh[0] = (const float*)d_in[11]; pa.bh[0] = (const float*)d_in[12];
    pa.wh[1] = (const float*)d_in[13]; pa.bh[1] = (const float*)d_in[14];
    pa.wh[2] = (const float*)d_in[15]; pa.bh[2] = (const float*)d_in[16];
    pa.wh[3] = (const float*)d_in[17]; pa.bh[3] = (const float*)d_in[18];

    short* a_pk = (short*)d_ws;                                    // 442368 B
    float* bias = (float*)((char*)d_ws + A_ELEMS * sizeof(short)); // 1024 B
    short* P    = (short*)((char*)d_ws + 443392);                  // 26.76 MB

    pack_weights<<<dim3(A_ELEMS / 256), dim3(256), 0, stream>>>(pa, a_pk, bias);
    pack_input <<<dim3(66, B_), dim3(256), 0, stream>>>(
        (const float*)d_in[0], (const float*)d_in[1], P);
    convlstm_main<<<dim3(B_ * 16), dim3(1024), 0, stream>>>(
        P, a_pk, bias, (const float*)d_in[2], (float*)d_out);
}

// Round 3
// 231.796 us; speedup vs baseline: 6.7103x; 6.7103x over previous
//
#include <hip/hip_runtime.h>

// ConvLSTM cell on MI355X (gfx950) — round 6 (= round 5 resubmit; infra flake).
// Implicit GEMM M=256 (4 gates x 64 oc), K=864 (96ch x 9 taps), N=131072.
// bf16 MFMA 32x32x16. Wave tile M=64 (4 gates x 16 oc -> lane-local LSTM
// epilogue) x N=64, acc = 64 AGPRs. 512 thr = 8 waves, grid 1024,
// (512,4) -> 128 regs/wave, 2 blocks/CU (HW cap: 64 AGPR acc => 4 waves/EU).
// Change vs round-3 (93.5us): double-buffered A staging.
// A repacked kk-major: [tap 9][kk 6][s 8][lane 64][j 8] so a half-tap
// (3 kk = 24 KB) is contiguous. LDS = 2 x 24 KB chunks; chunk c+1 is issued
// via global_load_lds BEFORE computing chunk c, so the vmcnt(0) drain in the
// end-of-chunk __syncthreads is ~free (loads landed under ~780 cyc of MFMA).
// B: direct global dwordx4 from P'[b][yy][pc12][xx66][8ch] (L1 serves the
// 4x og-wave redundancy).

#define B_   32
#define CIN  32
#define HC_  64
#define HH   64
#define WW   64

#define A_ELEMS (9 * 6 * 8 * 64 * 8)     // 221184 bf16 = 256 x 864 packed A
#define P_ROW   (12 * 66 * 8)            // shorts per P' row = 6336
#define CHUNK   12288                    // shorts per half-tap chunk (24 KB)

typedef __attribute__((ext_vector_type(8)))  short  short8;
typedef __attribute__((ext_vector_type(16))) float  floatx16;

struct PackArgs {
    const float* wx[4]; const float* wh[4];
    const float* bx[4]; const float* bh[4];
};

__device__ __forceinline__ short f2bf(float f) {
    unsigned u = __float_as_uint(f);
    u += 0x7FFFu + ((u >> 16) & 1u);     // round-to-nearest-even
    return (short)(u >> 16);
}

__device__ __forceinline__ void gl_lds16(const short* g, short* l) {
    __builtin_amdgcn_global_load_lds(
        (const __attribute__((address_space(1))) unsigned int*)g,
        (__attribute__((address_space(3))) unsigned int*)l, 16, 0, 0);
}

// ---- pack A: [tap 9][kk 6][s 8][lane 64][j 8] ------------------------------
// s = og*2+fi ; m32 = lane&31 ; gate = 2*fi + (m32>>4) ; oc = og*16 + (m32&15)
// c = kk*16 + (lane>>5)*8 + j  (A-operand: m = lane&31, k = (lane>>5)*8+j)
__global__ __launch_bounds__(256) void pack_weights(PackArgs pa, short* a_pk, float* bias) {
    int idx = blockIdx.x * 256 + threadIdx.x;
    if (idx < A_ELEMS) {
        int j    = idx & 7;
        int lane = (idx >> 3) & 63;
        int rest = idx >> 9;             // (tap*6 + kk)*8 + s
        int s    = rest & 7;
        int rest2 = rest >> 3;
        int kk   = rest2 % 6;
        int tap  = rest2 / 6;
        int og = s >> 1, fi = s & 1;
        int m32 = lane & 31;
        int gate = 2 * fi + (m32 >> 4);
        int oc   = og * 16 + (m32 & 15);
        int c    = kk * 16 + (lane >> 5) * 8 + j;
        int ky = tap / 3, kx = tap - 3 * ky;
        float v = (c < CIN)
            ? pa.wx[gate][((oc * CIN + c) * 3 + ky) * 3 + kx]
            : pa.wh[gate][((oc * HC_ + (c - CIN)) * 3 + ky) * 3 + kx];
        a_pk[idx] = f2bf(v);
    }
    if (idx < 256) {
        int gate = idx >> 6, oc = idx & 63;
        bias[idx] = pa.bx[gate][oc] + pa.bh[gate][oc];
    }
}

// ---- pack x||h -> P'[b][yy][pc 12][xx 66][8ch] bf16, zero borders ----------
__global__ __launch_bounds__(256) void pack_input(const float* __restrict__ x,
                                                  const float* __restrict__ h,
                                                  short* __restrict__ P) {
    const int yy = blockIdx.x, b = blockIdx.y;
    int4* prow4 = (int4*)(P + ((size_t)b * 66 + yy) * P_ROW);  // 792 chunks

    if (yy == 0 || yy == 65) {
        int4 z = {0, 0, 0, 0};
        for (int g = threadIdx.x; g < 792; g += 256) prow4[g] = z;
        return;
    }

    __shared__ short t[64 * 98];                     // [x][c], pad 96->98
    const int y = yy - 1;
    const int col = threadIdx.x & 63, cg = threadIdx.x >> 6;
    for (int c = cg; c < 96; c += 4) {
        float v = (c < CIN) ? x[((b * CIN + c) * HH + y) * WW + col]
                            : h[((b * HC_ + (c - CIN)) * HH + y) * WW + col];
        t[col * 98 + c] = f2bf(v);
    }
    __syncthreads();

    for (int g = threadIdx.x; g < 792; g += 256) {   // pc = g/66, xx = g%66
        int pc = g / 66, xx = g - 66 * pc;
        int4 val = {0, 0, 0, 0};
        if (xx >= 1 && xx <= 64) {
            const short* sp = &t[(xx - 1) * 98 + pc * 8];
            val.x = *(const int*)(sp + 0); val.y = *(const int*)(sp + 2);
            val.z = *(const int*)(sp + 4); val.w = *(const int*)(sp + 6);
        }
        prow4[g] = val;
    }
}

// ---- main: grid 1024 = (b 32)x(rowgroup 32 of 2 rows), 512 thr = 8 waves ---
// wave = og(0..3) x nh(0..1): M-tile = 4 gates x 16 oc (og), N = row y0+nh,
// 64 cols. acc[fi][ns] (fi = gate-pair, ns = col-half), 64 AGPR total.
// 18 half-tap chunks, double-buffered: stage(c+1) issued before compute(c).
__global__ __launch_bounds__(512, 4) void convlstm_main(
    const short* __restrict__ P, const short* __restrict__ a_pk,
    const float* __restrict__ bias, const float* __restrict__ cell,
    float* __restrict__ out)
{
    __shared__ __align__(16) short As[2][CHUNK];     // 2 x 24 KB dbuf

    const int tid = threadIdx.x;
    const int b  = blockIdx.x >> 5;
    const int y0 = (blockIdx.x & 31) * 2;

    const int wv = tid >> 6, lane = tid & 63;
    const int ln31 = lane & 31, hg = lane >> 5;
    const int og = wv & 3, nh = wv >> 2;
    const int y = y0 + nh;

    floatx16 acc[2][2];
    #pragma unroll
    for (int fi = 0; fi < 2; ++fi)
        #pragma unroll
        for (int ns = 0; ns < 2; ++ns)
            #pragma unroll
            for (int q = 0; q < 16; ++q) acc[fi][ns][q] = 0.f;

    // wave-constant pieces
    // chunk layout: [kkl 3][s 8][lane 64][j 8]; s = og*2+fi
    const int a_base = og * 1024 + lane * 8;             // + kkl*4096 + fi*512
    const int lnoff  = (hg * 66 + ln31) * 8;             // B per-lane offset

    // ---- prologue: stage chunk 0 into buffer 0 (1536 chunks / 512 thr = 3)
    {
        const short* src = a_pk;
        #pragma unroll
        for (int i = 0; i < 3; ++i)
            gl_lds16(src + (i * 512 + tid) * 8, &As[0][(i * 512 + wv * 64) * 8]);
    }
    __syncthreads();

    #pragma unroll
    for (int c = 0; c < 18; ++c) {
        const int cur = c & 1;
        // ---- issue next chunk's stage (lands during this chunk's MFMAs)
        if (c < 17) {
            const short* src = a_pk + (c + 1) * CHUNK;
            #pragma unroll
            for (int i = 0; i < 3; ++i)
                gl_lds16(src + (i * 512 + tid) * 8,
                         &As[cur ^ 1][(i * 512 + wv * 64) * 8]);
        }

        const int tap = c >> 1, half = c & 1;
        const int ky = tap / 3, kx = tap % 3;
        const short* Brow = P + ((size_t)(b * 66) + y + ky) * P_ROW + kx * 8 + lnoff;
        const short* Ac = As[cur];

        #pragma unroll
        for (int kkl = 0; kkl < 3; ++kkl) {
            const int kkg = half * 3 + kkl;
            short8 a0 = *(const short8*)&Ac[a_base + kkl * 4096];
            short8 a1 = *(const short8*)&Ac[a_base + kkl * 4096 + 512];
            short8 b0 = *(const short8*)&Brow[(2 * kkg * 66 + 0 ) * 8];
            short8 b1 = *(const short8*)&Brow[(2 * kkg * 66 + 32) * 8];
            acc[0][0] = __builtin_amdgcn_mfma_f32_32x32x16_bf16(a0, b0, acc[0][0], 0, 0, 0);
            acc[0][1] = __builtin_amdgcn_mfma_f32_32x32x16_bf16(a0, b1, acc[0][1], 0, 0, 0);
            acc[1][0] = __builtin_amdgcn_mfma_f32_32x32x16_bf16(a1, b0, acc[1][0], 0, 0, 0);
            acc[1][1] = __builtin_amdgcn_mfma_f32_32x32x16_bf16(a1, b1, acc[1][1], 0, 0, 0);
        }
        __syncthreads();   // vmcnt drain ~free: next stage issued ~780 cyc ago
    }

    // ---- lane-local LSTM epilogue --------------------------------------
    // C/D 32x32 map: col = ln31, row r32 = (r&3) + 4*hg + 8*(r>>2).
    // acc[fi][.] rows: r32<16 -> gate 2fi, oc16=r32 ; r32>=16 -> gate 2fi+1.
    const size_t plane = (size_t)B_ * HC_ * HH * WW;
    #pragma unroll
    for (int q = 0; q < 4; ++q)
    #pragma unroll
    for (int b8 = 0; b8 < 2; ++b8) {
        const int oc16 = q + 4 * hg + 8 * b8;
        const int oc = og * 16 + oc16;
        const float Bi = bias[oc],       Bf = bias[64 + oc];
        const float Bo = bias[128 + oc], Bg = bias[192 + oc];
        const int r_lo = q + 4 * b8, r_hi = q + 4 * (2 + b8);
        #pragma unroll
        for (int ns = 0; ns < 2; ++ns) {
            float zi = acc[0][ns][r_lo] + Bi;
            float zf = acc[0][ns][r_hi] + Bf;
            float zo = acc[1][ns][r_lo] + Bo;
            float zg = acc[1][ns][r_hi] + Bg;
            float ig = 1.f / (1.f + __expf(-zi));
            float fg = 1.f / (1.f + __expf(-zf));
            float sg = 1.f / (1.f + __expf(-zo));
            float e2 = __expf(2.f * zg);
            float gg = 1.f - 2.f / (e2 + 1.f);               // tanh(zg)
            const int x = ns * 32 + ln31;
            size_t off = ((size_t)(b * HC_ + oc) * HH + y) * WW + x;
            float cn = fg * cell[off] + ig * gg;
            float ec = __expf(2.f * cn);
            out[off] = sg * (1.f - 2.f / (ec + 1.f));        // h_new
            out[plane + off] = cn;                           // c_new
        }
    }
}

extern "C" void kernel_launch(void* const* d_in, const int* in_sizes, int n_in,
                              void* d_out, int out_size, void* d_ws, size_t ws_size,
                              hipStream_t stream) {
    PackArgs pa;
    pa.wx[0] = (const float*)d_in[3];  pa.bx[0] = (const float*)d_in[4];
    pa.wx[1] = (const float*)d_in[5];  pa.bx[1] = (const float*)d_in[6];
    pa.wx[2] = (const float*)d_in[7];  pa.bx[2] = (const float*)d_in[8];
    pa.wx[3] = (const float*)d_in[9];  pa.bx[3] = (const float*)d_in[10];
    pa.wh[0] = (const float*)d_in[11]; pa.bh[0] = (const float*)d_in[12];
    pa.wh[1] = (const float*)d_in[13]; pa.bh[1] = (const float*)d_in[14];
    pa.wh[2] = (const float*)d_in[15]; pa.bh[2] = (const float*)d_in[16];
    pa.wh[3] = (const float*)d_in[17]; pa.bh[3] = (const float*)d_in[18];

    short* a_pk = (short*)d_ws;                                    // 442368 B
    float* bias = (float*)((char*)d_ws + A_ELEMS * sizeof(short)); // 1024 B
    short* P    = (short*)((char*)d_ws + 443392);                  // 26.76 MB

    pack_weights<<<dim3(A_ELEMS / 256), dim3(256), 0, stream>>>(pa, a_pk, bias);
    pack_input <<<dim3(66, B_), dim3(256), 0, stream>>>(
        (const float*)d_in[0], (const float*)d_in[1], P);
    convlstm_main<<<dim3(B_ * 32), dim3(512), 0, stream>>>(
        P, a_pk, bias, (const float*)d_in[2], (float*)d_out);
}

// Round 4
// 222.617 us; speedup vs baseline: 6.9870x; 1.0412x over previous
//
#include <hip/hip_runtime.h>

// ConvLSTM cell on MI355X (gfx950) — round 7.
// Implicit GEMM M=256 (4 gates x 64 oc), K=864 (96ch x 9 taps), N=131072.
// bf16 MFMA 32x32x16. Wave tile M=64 (4 gates x 16 oc -> lane-local LSTM
// epilogue) x N=64. 512 thr = 8 waves, grid 1024, (512,4), 2 blocks/CU.
// Round-7 changes vs round-3/5 (90us, MfmaUtil 26%):
//  (1) B staged ONCE per block into LDS (4 contiguous P-rows = 50.7 KB) via
//      global_load_lds; B-frags now ds_read_b128 (kills ~885 MB of L2
//      traffic + L1 thrash from the 4x og-wave redundancy).
//  (2) A streamed as 54 x 8KB kk-chunks, TRIPLE-buffered, prefetch depth 2,
//      counted s_waitcnt vmcnt(1) + raw s_barrier per phase (never vmcnt(0)
//      in the loop — the T3/T4 fix for the __syncthreads full-drain stall).
// LDS 75264 B static (B 50688 + A 3x8192), 2 blocks/CU (150.5/160 KB).
// MFMA sequence identical to the passing round-3 kernel (bitwise-same acc).

#define B_   32
#define CIN  32
#define HC_  64
#define HH   64
#define WW   64

#define A_ELEMS (9 * 6 * 8 * 64 * 8)     // 221184 bf16 = 256 x 864 packed A
#define P_ROW   (12 * 66 * 8)            // shorts per P' row = 6336
#define AKK     4096                     // shorts per 1-kk A chunk (8 KB)
#define BLDS    25344                    // shorts of B in LDS (4 rows)

typedef __attribute__((ext_vector_type(8)))  short  short8;
typedef __attribute__((ext_vector_type(16))) float  floatx16;

struct PackArgs {
    const float* wx[4]; const float* wh[4];
    const float* bx[4]; const float* bh[4];
};

__device__ __forceinline__ short f2bf(float f) {
    unsigned u = __float_as_uint(f);
    u += 0x7FFFu + ((u >> 16) & 1u);     // round-to-nearest-even
    return (short)(u >> 16);
}

__device__ __forceinline__ void gl_lds16(const short* g, short* l) {
    __builtin_amdgcn_global_load_lds(
        (const __attribute__((address_space(1))) unsigned int*)g,
        (__attribute__((address_space(3))) unsigned int*)l, 16, 0, 0);
}

// ---- pack A: [tap 9][kk 6][s 8][lane 64][j 8] ------------------------------
// s = og*2+fi ; m32 = lane&31 ; gate = 2*fi + (m32>>4) ; oc = og*16 + (m32&15)
// c = kk*16 + (lane>>5)*8 + j  (A-operand: m = lane&31, k = (lane>>5)*8+j)
__global__ __launch_bounds__(256) void pack_weights(PackArgs pa, short* a_pk, float* bias) {
    int idx = blockIdx.x * 256 + threadIdx.x;
    if (idx < A_ELEMS) {
        int j    = idx & 7;
        int lane = (idx >> 3) & 63;
        int rest = idx >> 9;             // (tap*6 + kk)*8 + s
        int s    = rest & 7;
        int rest2 = rest >> 3;
        int kk   = rest2 % 6;
        int tap  = rest2 / 6;
        int og = s >> 1, fi = s & 1;
        int m32 = lane & 31;
        int gate = 2 * fi + (m32 >> 4);
        int oc   = og * 16 + (m32 & 15);
        int c    = kk * 16 + (lane >> 5) * 8 + j;
        int ky = tap / 3, kx = tap - 3 * ky;
        float v = (c < CIN)
            ? pa.wx[gate][((oc * CIN + c) * 3 + ky) * 3 + kx]
            : pa.wh[gate][((oc * HC_ + (c - CIN)) * 3 + ky) * 3 + kx];
        a_pk[idx] = f2bf(v);
    }
    if (idx < 256) {
        int gate = idx >> 6, oc = idx & 63;
        bias[idx] = pa.bx[gate][oc] + pa.bh[gate][oc];
    }
}

// ---- pack x||h -> P'[b][yy][pc 12][xx 66][8ch] bf16, zero borders ----------
__global__ __launch_bounds__(256) void pack_input(const float* __restrict__ x,
                                                  const float* __restrict__ h,
                                                  short* __restrict__ P) {
    const int yy = blockIdx.x, b = blockIdx.y;
    int4* prow4 = (int4*)(P + ((size_t)b * 66 + yy) * P_ROW);  // 792 chunks

    if (yy == 0 || yy == 65) {
        int4 z = {0, 0, 0, 0};
        for (int g = threadIdx.x; g < 792; g += 256) prow4[g] = z;
        return;
    }

    __shared__ short t[64 * 98];                     // [x][c], pad 96->98
    const int y = yy - 1;
    const int col = threadIdx.x & 63, cg = threadIdx.x >> 6;
    for (int c = cg; c < 96; c += 4) {
        float v = (c < CIN) ? x[((b * CIN + c) * HH + y) * WW + col]
                            : h[((b * HC_ + (c - CIN)) * HH + y) * WW + col];
        t[col * 98 + c] = f2bf(v);
    }
    __syncthreads();

    for (int g = threadIdx.x; g < 792; g += 256) {   // pc = g/66, xx = g%66
        int pc = g / 66, xx = g - 66 * pc;
        int4 val = {0, 0, 0, 0};
        if (xx >= 1 && xx <= 64) {
            const short* sp = &t[(xx - 1) * 98 + pc * 8];
            val.x = *(const int*)(sp + 0); val.y = *(const int*)(sp + 2);
            val.z = *(const int*)(sp + 4); val.w = *(const int*)(sp + 6);
        }
        prow4[g] = val;
    }
}

// ---- main: grid 1024 = (b 32)x(rowgroup 32 of 2 rows), 512 thr = 8 waves ---
// wave = og(0..3) x nh(0..1). acc[fi][ns], 64 AGPR.
// LDS: [B 4 rows x 6336][A buf0 4096][A buf1 4096][A buf2 4096] shorts.
// Phase c = tap*6+kk (54 phases): read A buf[c%3], issue stage(c+2) into
// buf[(c+2)%3]; close with s_waitcnt vmcnt(1) + s_barrier (counted, no drain).
__global__ __launch_bounds__(512, 4) void convlstm_main(
    const short* __restrict__ P, const short* __restrict__ a_pk,
    const float* __restrict__ bias, const float* __restrict__ cell,
    float* __restrict__ out)
{
    __shared__ __align__(16) short lds[BLDS + 3 * AKK];   // 75264 B

    const int tid = threadIdx.x;
    const int b  = blockIdx.x >> 5;
    const int y0 = (blockIdx.x & 31) * 2;

    const int wv = tid >> 6, lane = tid & 63;
    const int ln31 = lane & 31, hg = lane >> 5;
    const int og = wv & 3, nh = wv >> 2;
    const int y = y0 + nh;

    floatx16 acc[2][2];
    #pragma unroll
    for (int fi = 0; fi < 2; ++fi)
        #pragma unroll
        for (int ns = 0; ns < 2; ++ns)
            #pragma unroll
            for (int q = 0; q < 16; ++q) acc[fi][ns][q] = 0.f;

    short* Asl = lds + BLDS;                         // 3 x 4096 shorts
    const int a_rd  = og * 1024 + lane * 8;          // + (c%3)*4096 (+512 fi)
    const int b_rd  = nh * 6336 + hg * 528 + ln31 * 8;  // + ky*6336+kk*1056+kx*8

    // ---- prologue: B rows y0..y0+3 (3168 chunks) + A chunks 0,1 ----------
    {
        const short* Bsrc = P + ((size_t)(b * 66) + y0) * P_ROW;
        #pragma unroll
        for (int i = 0; i < 7; ++i) {
            int id = i * 512 + tid;
            if (id < 3168)
                gl_lds16(Bsrc + id * 8, lds + (i * 512 + wv * 64) * 8);
        }
        gl_lds16(a_pk + tid * 8,       Asl + wv * 64 * 8);            // chunk 0
        gl_lds16(a_pk + AKK + tid * 8, Asl + AKK + wv * 64 * 8);      // chunk 1
    }
    asm volatile("s_waitcnt vmcnt(1)" ::: "memory");  // B + chunk0 landed
    __builtin_amdgcn_s_barrier();
    __builtin_amdgcn_sched_barrier(0);

    #pragma unroll
    for (int c = 0; c < 54; ++c) {
        const int tap = c / 6, kk = c % 6;
        const int ky = tap / 3, kx = tap % 3;

        // issue stage(c+2) into buf[(c+2)%3] (1 gl_lds per thread)
        if (c < 52)
            gl_lds16(a_pk + (c + 2) * AKK + tid * 8,
                     Asl + ((c + 2) % 3) * AKK + wv * 64 * 8);

        const short* Ab = Asl + (c % 3) * AKK;
        const short* Bb = lds + b_rd + ky * 6336 + kk * 1056 + kx * 8;

        short8 a0 = *(const short8*)&Ab[a_rd];
        short8 a1 = *(const short8*)&Ab[a_rd + 512];
        short8 b0 = *(const short8*)&Bb[0];
        short8 b1 = *(const short8*)&Bb[256];
        acc[0][0] = __builtin_amdgcn_mfma_f32_32x32x16_bf16(a0, b0, acc[0][0], 0, 0, 0);
        acc[0][1] = __builtin_amdgcn_mfma_f32_32x32x16_bf16(a0, b1, acc[0][1], 0, 0, 0);
        acc[1][0] = __builtin_amdgcn_mfma_f32_32x32x16_bf16(a1, b0, acc[1][0], 0, 0, 0);
        acc[1][1] = __builtin_amdgcn_mfma_f32_32x32x16_bf16(a1, b1, acc[1][1], 0, 0, 0);

        // close phase: counted wait (stage(c+1) landed, stage(c+2) in flight)
        if (c < 52)       asm volatile("s_waitcnt vmcnt(1)" ::: "memory");
        else if (c == 52) asm volatile("s_waitcnt vmcnt(0)" ::: "memory");
        if (c < 53) {
            __builtin_amdgcn_s_barrier();
            __builtin_amdgcn_sched_barrier(0);
        }
    }

    // ---- lane-local LSTM epilogue --------------------------------------
    // C/D 32x32 map: col = ln31, row r32 = (r&3) + 4*hg + 8*(r>>2).
    // acc[fi][.] rows: r32<16 -> gate 2fi, oc16=r32 ; r32>=16 -> gate 2fi+1.
    const size_t plane = (size_t)B_ * HC_ * HH * WW;
    #pragma unroll
    for (int q = 0; q < 4; ++q)
    #pragma unroll
    for (int b8 = 0; b8 < 2; ++b8) {
        const int oc16 = q + 4 * hg + 8 * b8;
        const int oc = og * 16 + oc16;
        const float Bi = bias[oc],       Bf = bias[64 + oc];
        const float Bo = bias[128 + oc], Bg = bias[192 + oc];
        const int r_lo = q + 4 * b8, r_hi = q + 4 * (2 + b8);
        #pragma unroll
        for (int ns = 0; ns < 2; ++ns) {
            float zi = acc[0][ns][r_lo] + Bi;
            float zf = acc[0][ns][r_hi] + Bf;
            float zo = acc[1][ns][r_lo] + Bo;
            float zg = acc[1][ns][r_hi] + Bg;
            float ig = 1.f / (1.f + __expf(-zi));
            float fg = 1.f / (1.f + __expf(-zf));
            float sg = 1.f / (1.f + __expf(-zo));
            float e2 = __expf(2.f * zg);
            float gg = 1.f - 2.f / (e2 + 1.f);               // tanh(zg)
            const int x = ns * 32 + ln31;
            size_t off = ((size_t)(b * HC_ + oc) * HH + y) * WW + x;
            float cn = fg * cell[off] + ig * gg;
            float ec = __expf(2.f * cn);
            out[off] = sg * (1.f - 2.f / (ec + 1.f));        // h_new
            out[plane + off] = cn;                           // c_new
        }
    }
}

extern "C" void kernel_launch(void* const* d_in, const int* in_sizes, int n_in,
                              void* d_out, int out_size, void* d_ws, size_t ws_size,
                              hipStream_t stream) {
    PackArgs pa;
    pa.wx[0] = (const float*)d_in[3];  pa.bx[0] = (const float*)d_in[4];
    pa.wx[1] = (const float*)d_in[5];  pa.bx[1] = (const float*)d_in[6];
    pa.wx[2] = (const float*)d_in[7];  pa.bx[2] = (const float*)d_in[8];
    pa.wx[3] = (const float*)d_in[9];  pa.bx[3] = (const float*)d_in[10];
    pa.wh[0] = (const float*)d_in[11]; pa.bh[0] = (const float*)d_in[12];
    pa.wh[1] = (const float*)d_in[13]; pa.bh[1] = (const float*)d_in[14];
    pa.wh[2] = (const float*)d_in[15]; pa.bh[2] = (const float*)d_in[16];
    pa.wh[3] = (const float*)d_in[17]; pa.bh[3] = (const float*)d_in[18];

    short* a_pk = (short*)d_ws;                                    // 442368 B
    float* bias = (float*)((char*)d_ws + A_ELEMS * sizeof(short)); // 1024 B
    short* P    = (short*)((char*)d_ws + 443392);                  // 26.76 MB

    pack_weights<<<dim3(A_ELEMS / 256), dim3(256), 0, stream>>>(pa, a_pk, bias);
    pack_input <<<dim3(66, B_), dim3(256), 0, stream>>>(
        (const float*)d_in[0], (const float*)d_in[1], P);
    convlstm_main<<<dim3(B_ * 32), dim3(512), 0, stream>>>(
        P, a_pk, bias, (const float*)d_in[2], (float*)d_out);
}